// Round 1
// baseline (635.851 us; speedup 1.0000x reference)
//
#include <hip/hip_runtime.h>

#define NB 64
#define NN 1024
#define WDIM 64
#define RR 4
#define HID 512
#define XID 471
#define EPSF 1e-6f

// ---- d_out offsets (floats) ----
#define O_OUT   0
#define O_XI    16384
#define O_RW    46528
#define O_MEM   308672
#define O_USAGE 4502976

// ---- ws offsets (floats) ----
#define WS_READFLAT 0          // [64][256]
#define WS_H        16384      // [64][512]
#define WS_IFACE    49152      // [64][480]
#define WS_ALLOC    79872      // [64][1024]
#define WS_WW       145408     // [64][1024]
#define WS_V        210944     // [64][1024][8]
#define WS_ST       735232     // [64][8]
#define WS_DIAG     735744     // [64][1024]
#define WS_ROWAB    801280     // [64][1024][8]
#define WS_COLAB    1325568    // [64][1024][8]

// ---- iface per-b layout (stride 480) ----
#define IF_KN     0
#define IF_WKN    256
#define IF_ERASE  320
#define IF_WVEC   384
#define IF_RSTR   448
#define IF_FREE   452
#define IF_WSTR   456
#define IF_AG     457
#define IF_WG     458
#define IF_MODES  460
#define IF_STRIDE 480

__device__ __forceinline__ float sigmoidf_(float x) { return 1.0f / (1.0f + expf(-x)); }
__device__ __forceinline__ float oneplusf_(float x) {
  return 1.0f + ((x > 20.0f) ? x : log1pf(expf(x)));
}
__device__ __forceinline__ float readlane_f(float v, int l) {
  return __int_as_float(__builtin_amdgcn_readlane(__float_as_int(v), l));
}

// block reductions for 16-wave (1024-thread) blocks
__device__ __forceinline__ float blockSum16(float v, float* red) {
  #pragma unroll
  for (int s = 32; s; s >>= 1) v += __shfl_xor(v, s);
  __syncthreads();
  if ((threadIdx.x & 63) == 0) red[threadIdx.x >> 6] = v;
  __syncthreads();
  float s = 0.0f;
  #pragma unroll
  for (int i = 0; i < 16; ++i) s += red[i];
  return s;
}
__device__ __forceinline__ float blockMax16(float v, float* red) {
  #pragma unroll
  for (int s = 32; s; s >>= 1) v = fmaxf(v, __shfl_xor(v, s));
  __syncthreads();
  if ((threadIdx.x & 63) == 0) red[threadIdx.x >> 6] = v;
  __syncthreads();
  float m = red[0];
  #pragma unroll
  for (int i = 1; i < 16; ++i) m = fmaxf(m, red[i]);
  return m;
}

// 1) read_flat[b][r*64+w] = sum_n M[b,n,w]*rw[b,n,r]
__global__ __launch_bounds__(1024) void k_read_flat(const float* __restrict__ mem,
                                                    const float* __restrict__ rw,
                                                    float* __restrict__ ws) {
  __shared__ float red[1024];
  const int b = blockIdx.x, t = threadIdx.x;
  const int rwi = t & 255;
  const int r = rwi >> 6, w = rwi & 63;
  const int nq = t >> 8;
  const float* M  = mem + ((size_t)(b << 10) + (nq << 8)) * WDIM;
  const float* Rw = rw  + ((size_t)(b << 10) + (nq << 8)) * RR;
  float a0 = 0.f, a1 = 0.f, a2 = 0.f, a3 = 0.f;
  for (int n = 0; n < 256; n += 4) {
    a0 += M[(n + 0) * WDIM + w] * Rw[(n + 0) * RR + r];
    a1 += M[(n + 1) * WDIM + w] * Rw[(n + 1) * RR + r];
    a2 += M[(n + 2) * WDIM + w] * Rw[(n + 2) * RR + r];
    a3 += M[(n + 3) * WDIM + w] * Rw[(n + 3) * RR + r];
  }
  red[t] = (a0 + a1) + (a2 + a3);
  __syncthreads();
  if (t < 256)
    ws[WS_READFLAT + b * 256 + t] = red[t] + red[t + 256] + red[t + 512] + red[t + 768];
}

// 2) h = relu([x, read_flat] @ W1 + b1)
__global__ __launch_bounds__(512) void k_h(const float* __restrict__ x,
                                           const float* __restrict__ W1,
                                           const float* __restrict__ b1,
                                           float* __restrict__ ws) {
  __shared__ float cat[768];
  const int b = blockIdx.x, t = threadIdx.x;
  cat[t] = x[b * 512 + t];
  if (t < 256) cat[512 + t] = ws[WS_READFLAT + b * 256 + t];
  __syncthreads();
  float acc = b1[t];
  #pragma unroll 2
  for (int k = 0; k < 768; k += 4) {
    acc += cat[k] * W1[k * 512 + t];
    acc += cat[k + 1] * W1[(k + 1) * 512 + t];
    acc += cat[k + 2] * W1[(k + 2) * 512 + t];
    acc += cat[k + 3] * W1[(k + 3) * 512 + t];
  }
  ws[WS_H + b * 512 + t] = fmaxf(acc, 0.0f);
}

// 3) output = h@Wo + bo + read_flat@Wr + br
__global__ __launch_bounds__(256) void k_out(const float* __restrict__ Wo,
                                             const float* __restrict__ bo,
                                             const float* __restrict__ Wr,
                                             const float* __restrict__ br,
                                             const float* __restrict__ ws,
                                             float* __restrict__ out) {
  __shared__ float h[512];
  __shared__ float rf[256];
  const int b = blockIdx.x, t = threadIdx.x;
  h[t] = ws[WS_H + b * 512 + t];
  h[256 + t] = ws[WS_H + b * 512 + 256 + t];
  rf[t] = ws[WS_READFLAT + b * 256 + t];
  __syncthreads();
  float acc = bo[t] + br[t];
  #pragma unroll 4
  for (int j = 0; j < 512; ++j) acc += h[j] * Wo[j * 256 + t];
  #pragma unroll 4
  for (int j = 0; j < 256; ++j) acc += rf[j] * Wr[j * 256 + t];
  out[O_OUT + b * 256 + t] = acc;
}

// 4) xi = h@Wxi + bxi
__global__ __launch_bounds__(512) void k_xi(const float* __restrict__ Wxi,
                                            const float* __restrict__ bxi,
                                            const float* __restrict__ ws,
                                            float* __restrict__ out) {
  __shared__ float h[512];
  const int b = blockIdx.x, t = threadIdx.x;
  h[t] = ws[WS_H + b * 512 + t];
  __syncthreads();
  if (t >= XID) return;
  float acc = bxi[t];
  #pragma unroll 4
  for (int j = 0; j < 512; ++j) acc += h[j] * Wxi[j * XID + t];
  out[O_XI + b * XID + t] = acc;
}

// 5) interface activations (one wave per b)
__global__ __launch_bounds__(64) void k_iface(const float* __restrict__ out,
                                              float* __restrict__ ws) {
  const int b = blockIdx.x, w = threadIdx.x;
  const float* xi = out + O_XI + b * XID;
  float* f = ws + WS_IFACE + (size_t)b * IF_STRIDE;
  #pragma unroll
  for (int r = 0; r < 4; ++r) {
    float kv = xi[r * 64 + w];
    float ss = kv * kv;
    #pragma unroll
    for (int s = 32; s; s >>= 1) ss += __shfl_xor(ss, s);
    f[IF_KN + r * 64 + w] = kv * rsqrtf(ss + EPSF);
  }
  {
    float kv = xi[260 + w];
    float ss = kv * kv;
    #pragma unroll
    for (int s = 32; s; s >>= 1) ss += __shfl_xor(ss, s);
    f[IF_WKN + w] = kv * rsqrtf(ss + EPSF);
  }
  f[IF_ERASE + w] = sigmoidf_(xi[325 + w]);
  f[IF_WVEC + w] = xi[389 + w];
  if (w < 4) {
    f[IF_RSTR + w] = oneplusf_(xi[256 + w]);
    f[IF_FREE + w] = sigmoidf_(xi[453 + w]);
    float a = xi[459 + w * 3], bb = xi[459 + w * 3 + 1], c = xi[459 + w * 3 + 2];
    float m = fmaxf(a, fmaxf(bb, c));
    float ea = expf(a - m), eb = expf(bb - m), ec = expf(c - m);
    float s = ea + eb + ec;
    f[IF_MODES + w * 3] = ea / s;
    f[IF_MODES + w * 3 + 1] = eb / s;
    f[IF_MODES + w * 3 + 2] = ec / s;
  }
  if (w == 0) {
    f[IF_WSTR] = oneplusf_(xi[324]);
    f[IF_AG] = sigmoidf_(xi[457]);
    f[IF_WG] = sigmoidf_(xi[458]);
  }
}

// 6) usage_new
__global__ __launch_bounds__(256) void k_usage(const float* __restrict__ rw,
                                               const float* __restrict__ usage,
                                               const float* __restrict__ wwp,
                                               const float* __restrict__ ws,
                                               float* __restrict__ ousage) {
  const int i = blockIdx.x * 256 + threadIdx.x;
  const int b = i >> 10;
  const float* fr = ws + WS_IFACE + (size_t)b * IF_STRIDE + IF_FREE;
  const float4 r4 = *(const float4*)(rw + (size_t)i * 4);
  float ret = (1.0f - fr[0] * r4.x) * (1.0f - fr[1] * r4.y) *
              (1.0f - fr[2] * r4.z) * (1.0f - fr[3] * r4.w);
  float u = usage[i], w = wwp[i];
  ousage[i] = (u + w - u * w) * ret;
}

// 7) allocation: bitonic sort + product scan + scatter (one block per b)
__global__ __launch_bounds__(512) void k_alloc(const float* __restrict__ out,
                                               float* __restrict__ ws) {
  __shared__ float us[1024];
  __shared__ int idx[1024];
  __shared__ float cp[2][1024];
  const int b = blockIdx.x, t = threadIdx.x;
  us[t] = out[O_USAGE + (b << 10) + t];
  us[t + 512] = out[O_USAGE + (b << 10) + t + 512];
  idx[t] = t;
  idx[t + 512] = t + 512;
  __syncthreads();
  for (int k = 2; k <= 1024; k <<= 1) {
    for (int j = k >> 1; j > 0; j >>= 1) {
      int i = ((t & ~(j - 1)) << 1) | (t & (j - 1));
      int ix = i | j;
      bool up = ((i & k) == 0);
      float a = us[i], c = us[ix];
      int ia = idx[i], ic = idx[ix];
      bool gt = (a > c) || (a == c && ia > ic);
      if (gt == up) { us[i] = c; us[ix] = a; idx[i] = ic; idx[ix] = ia; }
      __syncthreads();
    }
  }
  cp[0][t] = us[t];
  cp[0][t + 512] = us[t + 512];
  __syncthreads();
  int src = 0;
  for (int off = 1; off < 1024; off <<= 1) {
    int dst = src ^ 1;
    for (int e = t; e < 1024; e += 512)
      cp[dst][e] = (e >= off) ? cp[src][e] * cp[src][e - off] : cp[src][e];
    __syncthreads();
    src = dst;
  }
  for (int e = t; e < 1024; e += 512) {
    float cpe = (e == 0) ? 1.0f : cp[src][e - 1];
    ws[WS_ALLOC + (b << 10) + idx[e]] = (1.0f - us[e]) * cpe;
  }
}

// 8) write-content softmax + ww + v-vectors + S/T + link diagonal
__global__ __launch_bounds__(1024) void k_wcww(const float* __restrict__ mem,
                                               const float* __restrict__ rw,
                                               const float* __restrict__ prec,
                                               const float* __restrict__ link,
                                               float* __restrict__ ws) {
  __shared__ float wkn[64];
  __shared__ float red[16];
  const int b = blockIdx.x, t = threadIdx.x;
  const float* f = ws + WS_IFACE + (size_t)b * IF_STRIDE;
  if (t < 64) wkn[t] = f[IF_WKN + t];
  __syncthreads();
  const float* Mrow = mem + ((size_t)(b << 10) + t) * WDIM;
  float dot = 0.0f, ssq = 0.0f;
  #pragma unroll
  for (int w = 0; w < 64; w += 4) {
    float4 m4 = *(const float4*)(Mrow + w);
    float4 k4 = *(const float4*)(&wkn[w]);
    dot += m4.x * k4.x + m4.y * k4.y + m4.z * k4.z + m4.w * k4.w;
    ssq += m4.x * m4.x + m4.y * m4.y + m4.z * m4.z + m4.w * m4.w;
  }
  float sim = dot * rsqrtf(ssq + EPSF) * f[IF_WSTR];
  float bmax = blockMax16(sim, red);
  float e = expf(sim - bmax);
  float bsum = blockSum16(e, red);
  float wc = e / bsum;
  float ag = f[IF_AG], wg = f[IF_WG];
  float ww = wg * (ag * ws[WS_ALLOC + (b << 10) + t] + (1.0f - ag) * wc);
  ws[WS_WW + (b << 10) + t] = ww;
  float4 r4 = *(const float4*)(rw + ((size_t)(b << 10) + t) * 4);
  float* vp = ws + WS_V + ((size_t)(b << 10) + t) * 8;
  vp[0] = r4.x; vp[1] = r4.y; vp[2] = r4.z; vp[3] = r4.w;
  vp[4] = ww * r4.x; vp[5] = ww * r4.y; vp[6] = ww * r4.z; vp[7] = ww * r4.w;
  ws[WS_DIAG + (b << 10) + t] = link[((size_t)(b << 10) + t) * 1024 + t];
  float p = prec[(b << 10) + t];
  float rv[4] = {r4.x, r4.y, r4.z, r4.w};
  #pragma unroll
  for (int r = 0; r < 4; ++r) {
    float s = blockSum16(p * rv[r], red);
    if (t == 0) ws[WS_ST + b * 8 + r] = s;
  }
  #pragma unroll
  for (int r = 0; r < 4; ++r) {
    float s = blockSum16(ww * rv[r], red);
    if (t == 0) ws[WS_ST + b * 8 + 4 + r] = s;
  }
}

// 9) memory_new (elementwise, float4)
__global__ __launch_bounds__(256) void k_memnew(const float* __restrict__ mem,
                                                const float* __restrict__ ws,
                                                float* __restrict__ omem) {
  const size_t i = (size_t)blockIdx.x * 256 + threadIdx.x; // over B*N*16 float4s
  const int w4 = (int)(i & 15);
  const size_t bn = i >> 4;
  const int b = (int)(bn >> 10);
  float ww = ws[WS_WW + bn];
  const float* f = ws + WS_IFACE + (size_t)b * IF_STRIDE;
  float4 e4 = *(const float4*)(f + IF_ERASE + (w4 << 2));
  float4 v4 = *(const float4*)(f + IF_WVEC + (w4 << 2));
  float4 m4 = ((const float4*)mem)[i];
  float4 o;
  o.x = m4.x * (1.0f - ww * e4.x) + ww * v4.x;
  o.y = m4.y * (1.0f - ww * e4.y) + ww * v4.y;
  o.z = m4.z * (1.0f - ww * e4.z) + ww * v4.z;
  o.w = m4.w * (1.0f - ww * e4.w) + ww * v4.w;
  ((float4*)omem)[i] = o;
}

// 10) link pass: one read of link -> rowAB (A,A') direct, colAB (B,B') atomics
__global__ __launch_bounds__(256) void k_link(const float* __restrict__ link,
                                              float* __restrict__ ws) {
  __shared__ float tiles[4][4096];
  const int rowband = blockIdx.x; // 0..15
  const int b = blockIdx.y;       // 0..63
  const int wv = threadIdx.x >> 6;
  const int lane = threadIdx.x & 63;
  float* tile = tiles[wv];
  const float* L = link + ((size_t)b << 20);
  const float* V = ws + WS_V + ((size_t)b << 13);
  const int i0 = rowband << 6;

  float u[8];
  {
    const float* up = V + (size_t)(i0 + lane) * 8;
    float4 a = *(const float4*)up;
    float4 c = *(const float4*)(up + 4);
    u[0] = a.x; u[1] = a.y; u[2] = a.z; u[3] = a.w;
    u[4] = c.x; u[5] = c.y; u[6] = c.z; u[7] = c.w;
  }
  float rowAcc[8];
  #pragma unroll
  for (int k = 0; k < 8; ++k) rowAcc[k] = 0.0f;

  #pragma unroll 1
  for (int tt = 0; tt < 4; ++tt) {
    const int tj = (tt << 2) + wv;
    const int j0 = tj << 6;
    // load 64x64 tile (wave-private), XOR-swizzled by 16B blocks
    #pragma unroll
    for (int s = 0; s < 16; ++s) {
      int fb = lane + (s << 6);
      int row = fb >> 4, jb = fb & 15;
      float4 d = *(const float4*)(L + (size_t)(i0 + row) * 1024 + j0 + (jb << 2));
      *(float4*)(tile + (row << 6) + ((jb ^ (row & 15)) << 2)) = d;
    }
    float vv[8];
    {
      const float* vp = V + (size_t)(j0 + lane) * 8;
      float4 a = *(const float4*)vp;
      float4 c = *(const float4*)(vp + 4);
      vv[0] = a.x; vv[1] = a.y; vv[2] = a.z; vv[3] = a.w;
      vv[4] = c.x; vv[5] = c.y; vv[6] = c.z; vv[7] = c.w;
    }
    // row pass: lane = row, readlane(v) broadcast
    #pragma unroll
    for (int jb = 0; jb < 16; ++jb) {
      float4 f4 = *(const float4*)(tile + (lane << 6) + ((jb ^ (lane & 15)) << 2));
      #pragma unroll
      for (int q = 0; q < 4; ++q) {
        float fq = (q == 0) ? f4.x : (q == 1) ? f4.y : (q == 2) ? f4.z : f4.w;
        const int j = (jb << 2) + q;
        #pragma unroll
        for (int k = 0; k < 8; ++k)
          rowAcc[k] = fmaf(fq, readlane_f(vv[k], j), rowAcc[k]);
      }
    }
    // col pass: lane = col, readlane(u) broadcast
    float colAcc[8];
    #pragma unroll
    for (int k = 0; k < 8; ++k) colAcc[k] = 0.0f;
    #pragma unroll
    for (int i = 0; i < 64; ++i) {
      float fq = tile[(i << 6) + (((lane >> 2) ^ (i & 15)) << 2) + (lane & 3)];
      #pragma unroll
      for (int k = 0; k < 8; ++k)
        colAcc[k] = fmaf(fq, readlane_f(u[k], i), colAcc[k]);
    }
    float* cp = ws + WS_COLAB + ((size_t)(b << 10) + j0 + lane) * 8;
    #pragma unroll
    for (int k = 0; k < 8; ++k) atomicAdd(cp + k, colAcc[k]);
  }
  // cross-wave row reduction, direct store
  __syncthreads();
  float* red = &tiles[0][0];
  #pragma unroll
  for (int k = 0; k < 8; ++k) red[((wv << 6) + lane) * 8 + k] = rowAcc[k];
  __syncthreads();
  if (wv == 0) {
    float* rp = ws + WS_ROWAB + ((size_t)(b << 10) + i0 + lane) * 8;
    #pragma unroll
    for (int k = 0; k < 8; ++k)
      rp[k] = red[lane * 8 + k] + red[(64 + lane) * 8 + k] +
              red[(128 + lane) * 8 + k] + red[(192 + lane) * 8 + k];
  }
}

// 11) read-content softmax + fwd/bwd combine -> rw_new
__global__ __launch_bounds__(1024) void k_final(const float* __restrict__ dout,
                                                const float* __restrict__ rw,
                                                const float* __restrict__ prec,
                                                const float* __restrict__ ws,
                                                float* __restrict__ orw) {
  __shared__ float kn[256];
  __shared__ float red[16];
  const int b = blockIdx.x, t = threadIdx.x;
  const float* f = ws + WS_IFACE + (size_t)b * IF_STRIDE;
  if (t < 256) kn[t] = f[IF_KN + t];
  __syncthreads();
  const float* Mrow = dout + O_MEM + ((size_t)(b << 10) + t) * WDIM;
  float dot0 = 0.f, dot1 = 0.f, dot2 = 0.f, dot3 = 0.f, ssq = 0.f;
  #pragma unroll
  for (int w = 0; w < 64; w += 4) {
    float4 m4 = *(const float4*)(Mrow + w);
    ssq += m4.x * m4.x + m4.y * m4.y + m4.z * m4.z + m4.w * m4.w;
    float4 k0 = *(const float4*)(&kn[w]);
    float4 k1 = *(const float4*)(&kn[64 + w]);
    float4 k2 = *(const float4*)(&kn[128 + w]);
    float4 k3 = *(const float4*)(&kn[192 + w]);
    dot0 += m4.x * k0.x + m4.y * k0.y + m4.z * k0.z + m4.w * k0.w;
    dot1 += m4.x * k1.x + m4.y * k1.y + m4.z * k1.z + m4.w * k1.w;
    dot2 += m4.x * k2.x + m4.y * k2.y + m4.z * k2.z + m4.w * k2.w;
    dot3 += m4.x * k3.x + m4.y * k3.y + m4.z * k3.z + m4.w * k3.w;
  }
  float rs = rsqrtf(ssq + EPSF);
  float sim[4] = {dot0 * rs * f[IF_RSTR + 0], dot1 * rs * f[IF_RSTR + 1],
                  dot2 * rs * f[IF_RSTR + 2], dot3 * rs * f[IF_RSTR + 3]};
  float cr[4];
  #pragma unroll
  for (int r = 0; r < 4; ++r) {
    float m = blockMax16(sim[r], red);
    float e = expf(sim[r] - m);
    float s = blockSum16(e, red);
    cr[r] = e / s;
  }
  const size_t bn = (size_t)(b << 10) + t;
  const float* ra = ws + WS_ROWAB + bn * 8;
  const float* ca = ws + WS_COLAB + bn * 8;
  float d = ws[WS_DIAG + bn];
  float w_ = ws[WS_WW + bn];
  float pn = prec[bn];
  float4 r4 = *(const float4*)(rw + bn * 4);
  float rv[4] = {r4.x, r4.y, r4.z, r4.w};
  const float* ST = ws + WS_ST + b * 8;
  float ow = 1.0f - w_;
  float res[4];
  #pragma unroll
  for (int r = 0; r < 4; ++r) {
    float A = ra[r], Ap = ra[4 + r], Bv = ca[r], Bp = ca[4 + r];
    float fwd = ow * (A - d * rv[r]) - (Ap - w_ * d * rv[r]) + w_ * (ST[r] - pn * rv[r]);
    float bwd = ow * (Bv - d * rv[r]) - (Bp - w_ * d * rv[r]) + pn * (ST[4 + r] - w_ * rv[r]);
    res[r] = f[IF_MODES + r * 3] * bwd + f[IF_MODES + r * 3 + 1] * cr[r] +
             f[IF_MODES + r * 3 + 2] * fwd;
  }
  float4 o = {res[0], res[1], res[2], res[3]};
  *(float4*)(orw + bn * 4) = o;
}

extern "C" void kernel_launch(void* const* d_in, const int* in_sizes, int n_in,
                              void* d_out, int out_size, void* d_ws, size_t ws_size,
                              hipStream_t stream) {
  const float* x     = (const float*)d_in[0];
  const float* rw    = (const float*)d_in[1];
  const float* mem   = (const float*)d_in[2];
  const float* usage = (const float*)d_in[3];
  const float* wwp   = (const float*)d_in[4];
  const float* link  = (const float*)d_in[5];
  const float* prec  = (const float*)d_in[6];
  const float* W1    = (const float*)d_in[7];
  const float* b1    = (const float*)d_in[8];
  const float* Wo    = (const float*)d_in[9];
  const float* bo    = (const float*)d_in[10];
  const float* Wr    = (const float*)d_in[11];
  const float* br    = (const float*)d_in[12];
  const float* Wxi   = (const float*)d_in[13];
  const float* bxi   = (const float*)d_in[14];
  float* out = (float*)d_out;
  float* ws = (float*)d_ws;

  hipMemsetAsync((char*)d_ws + (size_t)WS_COLAB * 4, 0, (size_t)524288 * 4, stream);

  k_read_flat<<<64, 1024, 0, stream>>>(mem, rw, ws);
  k_h<<<64, 512, 0, stream>>>(x, W1, b1, ws);
  k_out<<<64, 256, 0, stream>>>(Wo, bo, Wr, br, ws, out);
  k_xi<<<64, 512, 0, stream>>>(Wxi, bxi, ws, out);
  k_iface<<<64, 64, 0, stream>>>(out, ws);
  k_usage<<<256, 256, 0, stream>>>(rw, usage, wwp, ws, out + O_USAGE);
  k_alloc<<<64, 512, 0, stream>>>(out, ws);
  k_wcww<<<64, 1024, 0, stream>>>(mem, rw, prec, link, ws);
  k_memnew<<<4096, 256, 0, stream>>>(mem, ws, out + O_MEM);
  k_link<<<dim3(16, 64), 256, 0, stream>>>(link, ws);
  k_final<<<64, 1024, 0, stream>>>(out, rw, prec, ws, out + O_RW);
}

// Round 2
// 423.766 us; speedup vs baseline: 1.5005x; 1.5005x over previous
//
#include <hip/hip_runtime.h>

#define NB 64
#define NN 1024
#define WDIM 64
#define RR 4
#define HID 512
#define XID 471
#define EPSF 1e-6f

// ---- d_out offsets (floats) ----
#define O_OUT   0
#define O_XI    16384
#define O_RW    46528
#define O_MEM   308672
#define O_USAGE 4502976

// ---- ws offsets (floats) ----
#define WS_RFPART   0          // [4][64][256] read_flat partials
#define WS_H        65536      // [64][512]
#define WS_IFACE    98304      // [64][480]
#define WS_ALLOC    129024     // [64][1024]
#define WS_WW       194560     // [64][1024]
#define WS_V        260096     // [64][1024][8]
#define WS_ST       784384     // [64][8]
#define WS_DIAG     784896     // [64][1024]
#define WS_ROWAB    850432     // [64][1024][8]
#define WS_COLAB    1374720    // [64][1024][8]
#define WS_COLPART  1899008    // [8][64][1024][8] col partials (16.8 MB)

// ---- iface per-b layout (stride 480) ----
#define IF_KN     0
#define IF_WKN    256
#define IF_ERASE  320
#define IF_WVEC   384
#define IF_RSTR   448
#define IF_FREE   452
#define IF_WSTR   456
#define IF_AG     457
#define IF_WG     458
#define IF_MODES  460
#define IF_STRIDE 480

__device__ __forceinline__ float sigmoidf_(float x) { return 1.0f / (1.0f + expf(-x)); }
__device__ __forceinline__ float oneplusf_(float x) {
  return 1.0f + ((x > 20.0f) ? x : log1pf(expf(x)));
}
__device__ __forceinline__ float readlane_f(float v, int l) {
  return __int_as_float(__builtin_amdgcn_readlane(__float_as_int(v), l));
}

// block reductions for 16-wave (1024-thread) blocks
__device__ __forceinline__ float blockSum16(float v, float* red) {
  #pragma unroll
  for (int s = 32; s; s >>= 1) v += __shfl_xor(v, s);
  __syncthreads();
  if ((threadIdx.x & 63) == 0) red[threadIdx.x >> 6] = v;
  __syncthreads();
  float s = 0.0f;
  #pragma unroll
  for (int i = 0; i < 16; ++i) s += red[i];
  return s;
}
__device__ __forceinline__ float blockMax16(float v, float* red) {
  #pragma unroll
  for (int s = 32; s; s >>= 1) v = fmaxf(v, __shfl_xor(v, s));
  __syncthreads();
  if ((threadIdx.x & 63) == 0) red[threadIdx.x >> 6] = v;
  __syncthreads();
  float m = red[0];
  #pragma unroll
  for (int i = 1; i < 16; ++i) m = fmaxf(m, red[i]);
  return m;
}

// 1) read_flat partials: part[q][b][r*64+w] = sum_{n in q-range} M[b,n,w]*rw[b,n,r]
__global__ __launch_bounds__(1024) void k_read_flat(const float* __restrict__ mem,
                                                    const float* __restrict__ rw,
                                                    float* __restrict__ ws) {
  __shared__ float red[1024];
  const int q = blockIdx.x, b = blockIdx.y, t = threadIdx.x;
  const int rwi = t & 255;
  const int r = rwi >> 6, w = rwi & 63;
  const int ng = t >> 8;
  const int n0 = (q << 8) + (ng << 6);
  const float* M  = mem + ((size_t)(b << 10) + n0) * WDIM;
  const float* Rw = rw  + ((size_t)(b << 10) + n0) * RR;
  float a0 = 0.f, a1 = 0.f, a2 = 0.f, a3 = 0.f;
  for (int n = 0; n < 64; n += 4) {
    a0 += M[(n + 0) * WDIM + w] * Rw[(n + 0) * RR + r];
    a1 += M[(n + 1) * WDIM + w] * Rw[(n + 1) * RR + r];
    a2 += M[(n + 2) * WDIM + w] * Rw[(n + 2) * RR + r];
    a3 += M[(n + 3) * WDIM + w] * Rw[(n + 3) * RR + r];
  }
  red[t] = (a0 + a1) + (a2 + a3);
  __syncthreads();
  if (t < 256)
    ws[WS_RFPART + (((q << 6) + b) << 8) + t] =
        red[t] + red[t + 256] + red[t + 512] + red[t + 768];
}

// 2) h = relu([x, read_flat] @ W1 + b1)   (sums the 4 read_flat partials)
__global__ __launch_bounds__(512) void k_h(const float* __restrict__ x,
                                           const float* __restrict__ W1,
                                           const float* __restrict__ b1,
                                           float* __restrict__ ws) {
  __shared__ float cat[768];
  const int b = blockIdx.x, t = threadIdx.x;
  cat[t] = x[b * 512 + t];
  if (t < 256) {
    float s = 0.0f;
    #pragma unroll
    for (int q = 0; q < 4; ++q) s += ws[WS_RFPART + (((q << 6) + b) << 8) + t];
    cat[512 + t] = s;
  }
  __syncthreads();
  float acc = b1[t];
  #pragma unroll 2
  for (int k = 0; k < 768; k += 4) {
    acc += cat[k] * W1[k * 512 + t];
    acc += cat[k + 1] * W1[(k + 1) * 512 + t];
    acc += cat[k + 2] * W1[(k + 2) * 512 + t];
    acc += cat[k + 3] * W1[(k + 3) * 512 + t];
  }
  ws[WS_H + b * 512 + t] = fmaxf(acc, 0.0f);
}

// 3) output = h@Wo + bo + read_flat@Wr + br
__global__ __launch_bounds__(256) void k_out(const float* __restrict__ Wo,
                                             const float* __restrict__ bo,
                                             const float* __restrict__ Wr,
                                             const float* __restrict__ br,
                                             const float* __restrict__ ws,
                                             float* __restrict__ out) {
  __shared__ float h[512];
  __shared__ float rf[256];
  const int b = blockIdx.x, t = threadIdx.x;
  h[t] = ws[WS_H + b * 512 + t];
  h[256 + t] = ws[WS_H + b * 512 + 256 + t];
  {
    float s = 0.0f;
    #pragma unroll
    for (int q = 0; q < 4; ++q) s += ws[WS_RFPART + (((q << 6) + b) << 8) + t];
    rf[t] = s;
  }
  __syncthreads();
  float acc = bo[t] + br[t];
  #pragma unroll 4
  for (int j = 0; j < 512; ++j) acc += h[j] * Wo[j * 256 + t];
  #pragma unroll 4
  for (int j = 0; j < 256; ++j) acc += rf[j] * Wr[j * 256 + t];
  out[O_OUT + b * 256 + t] = acc;
}

// 4) xi = h@Wxi + bxi
__global__ __launch_bounds__(512) void k_xi(const float* __restrict__ Wxi,
                                            const float* __restrict__ bxi,
                                            const float* __restrict__ ws,
                                            float* __restrict__ out) {
  __shared__ float h[512];
  const int b = blockIdx.x, t = threadIdx.x;
  h[t] = ws[WS_H + b * 512 + t];
  __syncthreads();
  if (t >= XID) return;
  float acc = bxi[t];
  #pragma unroll 4
  for (int j = 0; j < 512; ++j) acc += h[j] * Wxi[j * XID + t];
  out[O_XI + b * XID + t] = acc;
}

// 5) interface activations (one wave per b)
__global__ __launch_bounds__(64) void k_iface(const float* __restrict__ out,
                                              float* __restrict__ ws) {
  const int b = blockIdx.x, w = threadIdx.x;
  const float* xi = out + O_XI + b * XID;
  float* f = ws + WS_IFACE + (size_t)b * IF_STRIDE;
  #pragma unroll
  for (int r = 0; r < 4; ++r) {
    float kv = xi[r * 64 + w];
    float ss = kv * kv;
    #pragma unroll
    for (int s = 32; s; s >>= 1) ss += __shfl_xor(ss, s);
    f[IF_KN + r * 64 + w] = kv * rsqrtf(ss + EPSF);
  }
  {
    float kv = xi[260 + w];
    float ss = kv * kv;
    #pragma unroll
    for (int s = 32; s; s >>= 1) ss += __shfl_xor(ss, s);
    f[IF_WKN + w] = kv * rsqrtf(ss + EPSF);
  }
  f[IF_ERASE + w] = sigmoidf_(xi[325 + w]);
  f[IF_WVEC + w] = xi[389 + w];
  if (w < 4) {
    f[IF_RSTR + w] = oneplusf_(xi[256 + w]);
    f[IF_FREE + w] = sigmoidf_(xi[453 + w]);
    float a = xi[459 + w * 3], bb = xi[459 + w * 3 + 1], c = xi[459 + w * 3 + 2];
    float m = fmaxf(a, fmaxf(bb, c));
    float ea = expf(a - m), eb = expf(bb - m), ec = expf(c - m);
    float s = ea + eb + ec;
    f[IF_MODES + w * 3] = ea / s;
    f[IF_MODES + w * 3 + 1] = eb / s;
    f[IF_MODES + w * 3 + 2] = ec / s;
  }
  if (w == 0) {
    f[IF_WSTR] = oneplusf_(xi[324]);
    f[IF_AG] = sigmoidf_(xi[457]);
    f[IF_WG] = sigmoidf_(xi[458]);
  }
}

// 6) usage_new
__global__ __launch_bounds__(256) void k_usage(const float* __restrict__ rw,
                                               const float* __restrict__ usage,
                                               const float* __restrict__ wwp,
                                               const float* __restrict__ ws,
                                               float* __restrict__ ousage) {
  const int i = blockIdx.x * 256 + threadIdx.x;
  const int b = i >> 10;
  const float* fr = ws + WS_IFACE + (size_t)b * IF_STRIDE + IF_FREE;
  const float4 r4 = *(const float4*)(rw + (size_t)i * 4);
  float ret = (1.0f - fr[0] * r4.x) * (1.0f - fr[1] * r4.y) *
              (1.0f - fr[2] * r4.z) * (1.0f - fr[3] * r4.w);
  float u = usage[i], w = wwp[i];
  ousage[i] = (u + w - u * w) * ret;
}

// 7) allocation: bitonic sort + product scan + scatter (one block per b)
__global__ __launch_bounds__(512) void k_alloc(const float* __restrict__ out,
                                               float* __restrict__ ws) {
  __shared__ float us[1024];
  __shared__ int idx[1024];
  __shared__ float cp[2][1024];
  const int b = blockIdx.x, t = threadIdx.x;
  us[t] = out[O_USAGE + (b << 10) + t];
  us[t + 512] = out[O_USAGE + (b << 10) + t + 512];
  idx[t] = t;
  idx[t + 512] = t + 512;
  __syncthreads();
  for (int k = 2; k <= 1024; k <<= 1) {
    for (int j = k >> 1; j > 0; j >>= 1) {
      int i = ((t & ~(j - 1)) << 1) | (t & (j - 1));
      int ix = i | j;
      bool up = ((i & k) == 0);
      float a = us[i], c = us[ix];
      int ia = idx[i], ic = idx[ix];
      bool gt = (a > c) || (a == c && ia > ic);
      if (gt == up) { us[i] = c; us[ix] = a; idx[i] = ic; idx[ix] = ia; }
      __syncthreads();
    }
  }
  cp[0][t] = us[t];
  cp[0][t + 512] = us[t + 512];
  __syncthreads();
  int src = 0;
  for (int off = 1; off < 1024; off <<= 1) {
    int dst = src ^ 1;
    for (int e = t; e < 1024; e += 512)
      cp[dst][e] = (e >= off) ? cp[src][e] * cp[src][e - off] : cp[src][e];
    __syncthreads();
    src = dst;
  }
  for (int e = t; e < 1024; e += 512) {
    float cpe = (e == 0) ? 1.0f : cp[src][e - 1];
    ws[WS_ALLOC + (b << 10) + idx[e]] = (1.0f - us[e]) * cpe;
  }
}

// 8) write-content softmax + ww + v-vectors + S/T + link diagonal
__global__ __launch_bounds__(1024) void k_wcww(const float* __restrict__ mem,
                                               const float* __restrict__ rw,
                                               const float* __restrict__ prec,
                                               const float* __restrict__ link,
                                               float* __restrict__ ws) {
  __shared__ float wkn[64];
  __shared__ float red[16];
  const int b = blockIdx.x, t = threadIdx.x;
  const float* f = ws + WS_IFACE + (size_t)b * IF_STRIDE;
  if (t < 64) wkn[t] = f[IF_WKN + t];
  __syncthreads();
  const float* Mrow = mem + ((size_t)(b << 10) + t) * WDIM;
  float dot = 0.0f, ssq = 0.0f;
  #pragma unroll
  for (int w = 0; w < 64; w += 4) {
    float4 m4 = *(const float4*)(Mrow + w);
    float4 k4 = *(const float4*)(&wkn[w]);
    dot += m4.x * k4.x + m4.y * k4.y + m4.z * k4.z + m4.w * k4.w;
    ssq += m4.x * m4.x + m4.y * m4.y + m4.z * m4.z + m4.w * m4.w;
  }
  float sim = dot * rsqrtf(ssq + EPSF) * f[IF_WSTR];
  float bmax = blockMax16(sim, red);
  float e = expf(sim - bmax);
  float bsum = blockSum16(e, red);
  float wc = e / bsum;
  float ag = f[IF_AG], wg = f[IF_WG];
  float ww = wg * (ag * ws[WS_ALLOC + (b << 10) + t] + (1.0f - ag) * wc);
  ws[WS_WW + (b << 10) + t] = ww;
  float4 r4 = *(const float4*)(rw + ((size_t)(b << 10) + t) * 4);
  float* vp = ws + WS_V + ((size_t)(b << 10) + t) * 8;
  vp[0] = r4.x; vp[1] = r4.y; vp[2] = r4.z; vp[3] = r4.w;
  vp[4] = ww * r4.x; vp[5] = ww * r4.y; vp[6] = ww * r4.z; vp[7] = ww * r4.w;
  ws[WS_DIAG + (b << 10) + t] = link[((size_t)(b << 10) + t) * 1024 + t];
  float p = prec[(b << 10) + t];
  float rv[4] = {r4.x, r4.y, r4.z, r4.w};
  #pragma unroll
  for (int r = 0; r < 4; ++r) {
    float s = blockSum16(p * rv[r], red);
    if (t == 0) ws[WS_ST + b * 8 + r] = s;
  }
  #pragma unroll
  for (int r = 0; r < 4; ++r) {
    float s = blockSum16(ww * rv[r], red);
    if (t == 0) ws[WS_ST + b * 8 + 4 + r] = s;
  }
}

// 9) memory_new (elementwise, float4)
__global__ __launch_bounds__(256) void k_memnew(const float* __restrict__ mem,
                                                const float* __restrict__ ws,
                                                float* __restrict__ omem) {
  const size_t i = (size_t)blockIdx.x * 256 + threadIdx.x; // over B*N*16 float4s
  const int w4 = (int)(i & 15);
  const size_t bn = i >> 4;
  const int b = (int)(bn >> 10);
  float ww = ws[WS_WW + bn];
  const float* f = ws + WS_IFACE + (size_t)b * IF_STRIDE;
  float4 e4 = *(const float4*)(f + IF_ERASE + (w4 << 2));
  float4 v4 = *(const float4*)(f + IF_WVEC + (w4 << 2));
  float4 m4 = ((const float4*)mem)[i];
  float4 o;
  o.x = m4.x * (1.0f - ww * e4.x) + ww * v4.x;
  o.y = m4.y * (1.0f - ww * e4.y) + ww * v4.y;
  o.z = m4.z * (1.0f - ww * e4.z) + ww * v4.z;
  o.w = m4.w * (1.0f - ww * e4.w) + ww * v4.w;
  ((float4*)omem)[i] = o;
}

// 10) link pass: one read of link. Block = (rowgroup of 128 rows, b).
//     rowAB complete per block (direct store); colAB partial per rowgroup
//     (direct store, NO atomics), reduced by k_colred.
__global__ __launch_bounds__(256) void k_link(const float* __restrict__ link,
                                              float* __restrict__ ws) {
  __shared__ float tiles[4][4096];
  const int rg = blockIdx.x;      // 0..7
  const int b = blockIdx.y;       // 0..63
  const int wv = threadIdx.x >> 6;
  const int lane = threadIdx.x & 63;
  float* tile = tiles[wv];
  const float* L = link + ((size_t)b << 20);
  const float* V = ws + WS_V + ((size_t)b << 13);
  const int i0 = rg << 7;

  // u vectors for the two 64-row subbands (lane <-> row)
  float u0[8], u1[8];
  {
    const float* up = V + (size_t)(i0 + lane) * 8;
    float4 a = *(const float4*)up, c = *(const float4*)(up + 4);
    u0[0]=a.x; u0[1]=a.y; u0[2]=a.z; u0[3]=a.w;
    u0[4]=c.x; u0[5]=c.y; u0[6]=c.z; u0[7]=c.w;
    up = V + (size_t)(i0 + 64 + lane) * 8;
    a = *(const float4*)up; c = *(const float4*)(up + 4);
    u1[0]=a.x; u1[1]=a.y; u1[2]=a.z; u1[3]=a.w;
    u1[4]=c.x; u1[5]=c.y; u1[6]=c.z; u1[7]=c.w;
  }
  float rowAcc0[8], rowAcc1[8];
  #pragma unroll
  for (int k = 0; k < 8; ++k) { rowAcc0[k] = 0.0f; rowAcc1[k] = 0.0f; }

  #pragma unroll 1
  for (int tt = 0; tt < 4; ++tt) {
    const int tj = (tt << 2) + wv;
    const int j0 = tj << 6;
    float vv[8];
    {
      const float* vp = V + (size_t)(j0 + lane) * 8;
      float4 a = *(const float4*)vp, c = *(const float4*)(vp + 4);
      vv[0]=a.x; vv[1]=a.y; vv[2]=a.z; vv[3]=a.w;
      vv[4]=c.x; vv[5]=c.y; vv[6]=c.z; vv[7]=c.w;
    }
    float colAcc[8];
    #pragma unroll
    for (int k = 0; k < 8; ++k) colAcc[k] = 0.0f;

    #pragma unroll
    for (int sb = 0; sb < 2; ++sb) {
      const int r0 = i0 + (sb << 6);
      // load 64x64 tile (wave-private), XOR-swizzled by 16B blocks
      #pragma unroll
      for (int s = 0; s < 16; ++s) {
        int fb = lane + (s << 6);
        int row = fb >> 4, jb = fb & 15;
        float4 d = *(const float4*)(L + (size_t)(r0 + row) * 1024 + j0 + (jb << 2));
        *(float4*)(tile + (row << 6) + ((jb ^ (row & 15)) << 2)) = d;
      }
      // row pass: lane = row
      #pragma unroll
      for (int jb = 0; jb < 16; ++jb) {
        float4 f4 = *(const float4*)(tile + (lane << 6) + ((jb ^ (lane & 15)) << 2));
        #pragma unroll
        for (int q = 0; q < 4; ++q) {
          float fq = (q == 0) ? f4.x : (q == 1) ? f4.y : (q == 2) ? f4.z : f4.w;
          const int j = (jb << 2) + q;
          #pragma unroll
          for (int k = 0; k < 8; ++k) {
            float vk = readlane_f(vv[k], j);
            if (sb == 0) rowAcc0[k] = fmaf(fq, vk, rowAcc0[k]);
            else         rowAcc1[k] = fmaf(fq, vk, rowAcc1[k]);
          }
        }
      }
      // col pass: lane = col
      #pragma unroll
      for (int i = 0; i < 64; ++i) {
        float fq = tile[(i << 6) + ((((lane >> 2) ^ (i & 15)) << 2) | (lane & 3))];
        #pragma unroll
        for (int k = 0; k < 8; ++k) {
          float uk = readlane_f(sb == 0 ? u0[k] : u1[k], i);
          colAcc[k] = fmaf(fq, uk, colAcc[k]);
        }
      }
    }
    // direct store of col partial for this (rg, coltile)
    float* cp = ws + WS_COLPART + ((((size_t)rg << 6) + (size_t)b) << 13) +
                (size_t)(j0 + lane) * 8;
    float4 c0 = {colAcc[0], colAcc[1], colAcc[2], colAcc[3]};
    float4 c1 = {colAcc[4], colAcc[5], colAcc[6], colAcc[7]};
    *(float4*)cp = c0;
    *(float4*)(cp + 4) = c1;
  }

  // cross-wave row reduction, direct store (block covers full row width)
  __syncthreads();
  float* red = &tiles[0][0]; // [wv][sb][row][k] = 4*2*64*8 = 4096 floats
  #pragma unroll
  for (int k = 0; k < 8; ++k) {
    red[(((wv << 1) + 0) * 64 + lane) * 8 + k] = rowAcc0[k];
    red[(((wv << 1) + 1) * 64 + lane) * 8 + k] = rowAcc1[k];
  }
  __syncthreads();
  {
    const int pair = threadIdx.x >> 1;       // 0..127 = sb*64+row
    const int kh = (threadIdx.x & 1) << 2;   // 0 or 4
    const int sb = pair >> 6, row = pair & 63;
    float4 s = {0.f, 0.f, 0.f, 0.f};
    #pragma unroll
    for (int w = 0; w < 4; ++w) {
      float4 v = *(const float4*)(red + (((w << 1) + sb) * 64 + row) * 8 + kh);
      s.x += v.x; s.y += v.y; s.z += v.z; s.w += v.w;
    }
    float* op = ws + WS_ROWAB + ((size_t)(b << 10) + i0 + (sb << 6) + row) * 8 + kh;
    *(float4*)op = s;
  }
}

// 10b) reduce the 8 col partials -> WS_COLAB
__global__ __launch_bounds__(256) void k_colred(float* __restrict__ ws) {
  const int i4 = blockIdx.x * 256 + threadIdx.x; // float4 index, 0..131071
  const float4* p = (const float4*)(ws + WS_COLPART);
  float4 s = p[i4];
  #pragma unroll
  for (int rg = 1; rg < 8; ++rg) {
    float4 v = p[(size_t)rg * 131072 + i4];
    s.x += v.x; s.y += v.y; s.z += v.z; s.w += v.w;
  }
  ((float4*)(ws + WS_COLAB))[i4] = s;
}

// 11) read-content softmax + fwd/bwd combine -> rw_new
__global__ __launch_bounds__(1024) void k_final(const float* __restrict__ dout,
                                                const float* __restrict__ rw,
                                                const float* __restrict__ prec,
                                                const float* __restrict__ ws,
                                                float* __restrict__ orw) {
  __shared__ float kn[256];
  __shared__ float red[16];
  const int b = blockIdx.x, t = threadIdx.x;
  const float* f = ws + WS_IFACE + (size_t)b * IF_STRIDE;
  if (t < 256) kn[t] = f[IF_KN + t];
  __syncthreads();
  const float* Mrow = dout + O_MEM + ((size_t)(b << 10) + t) * WDIM;
  float dot0 = 0.f, dot1 = 0.f, dot2 = 0.f, dot3 = 0.f, ssq = 0.f;
  #pragma unroll
  for (int w = 0; w < 64; w += 4) {
    float4 m4 = *(const float4*)(Mrow + w);
    ssq += m4.x * m4.x + m4.y * m4.y + m4.z * m4.z + m4.w * m4.w;
    float4 k0 = *(const float4*)(&kn[w]);
    float4 k1 = *(const float4*)(&kn[64 + w]);
    float4 k2 = *(const float4*)(&kn[128 + w]);
    float4 k3 = *(const float4*)(&kn[192 + w]);
    dot0 += m4.x * k0.x + m4.y * k0.y + m4.z * k0.z + m4.w * k0.w;
    dot1 += m4.x * k1.x + m4.y * k1.y + m4.z * k1.z + m4.w * k1.w;
    dot2 += m4.x * k2.x + m4.y * k2.y + m4.z * k2.z + m4.w * k2.w;
    dot3 += m4.x * k3.x + m4.y * k3.y + m4.z * k3.z + m4.w * k3.w;
  }
  float rs = rsqrtf(ssq + EPSF);
  float sim[4] = {dot0 * rs * f[IF_RSTR + 0], dot1 * rs * f[IF_RSTR + 1],
                  dot2 * rs * f[IF_RSTR + 2], dot3 * rs * f[IF_RSTR + 3]};
  float cr[4];
  #pragma unroll
  for (int r = 0; r < 4; ++r) {
    float m = blockMax16(sim[r], red);
    float e = expf(sim[r] - m);
    float s = blockSum16(e, red);
    cr[r] = e / s;
  }
  const size_t bn = (size_t)(b << 10) + t;
  const float* ra = ws + WS_ROWAB + bn * 8;
  const float* ca = ws + WS_COLAB + bn * 8;
  float d = ws[WS_DIAG + bn];
  float w_ = ws[WS_WW + bn];
  float pn = prec[bn];
  float4 r4 = *(const float4*)(rw + bn * 4);
  float rv[4] = {r4.x, r4.y, r4.z, r4.w};
  const float* ST = ws + WS_ST + b * 8;
  float ow = 1.0f - w_;
  float res[4];
  #pragma unroll
  for (int r = 0; r < 4; ++r) {
    float A = ra[r], Ap = ra[4 + r], Bv = ca[r], Bp = ca[4 + r];
    float fwd = ow * (A - d * rv[r]) - (Ap - w_ * d * rv[r]) + w_ * (ST[r] - pn * rv[r]);
    float bwd = ow * (Bv - d * rv[r]) - (Bp - w_ * d * rv[r]) + pn * (ST[4 + r] - w_ * rv[r]);
    res[r] = f[IF_MODES + r * 3] * bwd + f[IF_MODES + r * 3 + 1] * cr[r] +
             f[IF_MODES + r * 3 + 2] * fwd;
  }
  float4 o = {res[0], res[1], res[2], res[3]};
  *(float4*)(orw + bn * 4) = o;
}

extern "C" void kernel_launch(void* const* d_in, const int* in_sizes, int n_in,
                              void* d_out, int out_size, void* d_ws, size_t ws_size,
                              hipStream_t stream) {
  const float* x     = (const float*)d_in[0];
  const float* rw    = (const float*)d_in[1];
  const float* mem   = (const float*)d_in[2];
  const float* usage = (const float*)d_in[3];
  const float* wwp   = (const float*)d_in[4];
  const float* link  = (const float*)d_in[5];
  const float* prec  = (const float*)d_in[6];
  const float* W1    = (const float*)d_in[7];
  const float* b1    = (const float*)d_in[8];
  const float* Wo    = (const float*)d_in[9];
  const float* bo    = (const float*)d_in[10];
  const float* Wr    = (const float*)d_in[11];
  const float* br    = (const float*)d_in[12];
  const float* Wxi   = (const float*)d_in[13];
  const float* bxi   = (const float*)d_in[14];
  float* out = (float*)d_out;
  float* ws = (float*)d_ws;

  k_read_flat<<<dim3(4, 64), 1024, 0, stream>>>(mem, rw, ws);
  k_h<<<64, 512, 0, stream>>>(x, W1, b1, ws);
  k_out<<<64, 256, 0, stream>>>(Wo, bo, Wr, br, ws, out);
  k_xi<<<64, 512, 0, stream>>>(Wxi, bxi, ws, out);
  k_iface<<<64, 64, 0, stream>>>(out, ws);
  k_usage<<<256, 256, 0, stream>>>(rw, usage, wwp, ws, out + O_USAGE);
  k_alloc<<<64, 512, 0, stream>>>(out, ws);
  k_wcww<<<64, 1024, 0, stream>>>(mem, rw, prec, link, ws);
  k_memnew<<<4096, 256, 0, stream>>>(mem, ws, out + O_MEM);
  k_link<<<dim3(8, 64), 256, 0, stream>>>(link, ws);
  k_colred<<<512, 256, 0, stream>>>(ws);
  k_final<<<64, 1024, 0, stream>>>(out, rw, prec, ws, out + O_RW);
}